// Round 3
// baseline (617.099 us; speedup 1.0000x reference)
//
#include <hip/hip_runtime.h>

// Fixed problem dims from setup_inputs(): B=2048, D=1024, H=512, K=32, OUT=2
#define BB 2048
#define DD 1024
#define HH 512
#define KK 32

// ---------- workspace layout (float element offsets) ----------
#define OFF_H0    ((size_t)0)         // [2048,512]  f32
#define OFF_H1    ((size_t)1048576)   // [2048,512]  f32
#define OFF_LG    ((size_t)2097152)   // [2048,1024] f32 (softmaxed in place)
#define OFF_NEWIN ((size_t)4194304)   // [2048,1024] f32
#define OFF_HP    ((size_t)6291456)   // [2048,512]  f32
// total = 7340032 floats = 29.4 MB (rounds 1-2 wrote this much without faulting)

// ---------- fp32 tiled GEMM: C[M,N] = act(A[M,K] @ W[K,N] + bias) ----------
// 64x64 tile, BK=16, 256 threads, 4x4 accum per thread. M,N % 64 == 0, K % 16 == 0.
__global__ __launch_bounds__(256) void gemm_f32(
    const float* __restrict__ A, const float* __restrict__ W,
    const float* __restrict__ bias, float* __restrict__ C,
    int M, int N, int Kd, int act)
{
    __shared__ float As[16][64];
    __shared__ float Bs[16][64];
    const int tid = threadIdx.x;
    const int tx = tid & 15, ty = tid >> 4;
    const int bm = blockIdx.y * 64, bn = blockIdx.x * 64;

    float acc[4][4] = {};

    const int ar = tid >> 2;          // 0..63 (A tile row)
    const int ak = (tid & 3) * 4;     // 0,4,8,12 (A tile k)
    const int br = tid >> 4;          // 0..15 (B tile k)
    const int bc = (tid & 15) * 4;    // 0..60 (B tile col)

    for (int k0 = 0; k0 < Kd; k0 += 16) {
        const float4 av = *(const float4*)(A + (size_t)(bm + ar) * Kd + k0 + ak);
        const float4 bv = *(const float4*)(W + (size_t)(k0 + br) * N + bn + bc);
        __syncthreads();
        As[ak + 0][ar] = av.x; As[ak + 1][ar] = av.y;
        As[ak + 2][ar] = av.z; As[ak + 3][ar] = av.w;
        *(float4*)&Bs[br][bc] = bv;
        __syncthreads();
#pragma unroll
        for (int kk = 0; kk < 16; ++kk) {
            float a[4], b[4];
            *(float4*)a = *(const float4*)&As[kk][ty * 4];
            *(float4*)b = *(const float4*)&Bs[kk][tx * 4];
#pragma unroll
            for (int i = 0; i < 4; ++i)
#pragma unroll
                for (int j = 0; j < 4; ++j) acc[i][j] += a[i] * b[j];
        }
    }

    float bj[4];
    *(float4*)bj = *(const float4*)(bias + bn + tx * 4);
#pragma unroll
    for (int i = 0; i < 4; ++i) {
        const int row = bm + ty * 4 + i;
        float4 v;
        v.x = acc[i][0] + bj[0]; v.y = acc[i][1] + bj[1];
        v.z = acc[i][2] + bj[2]; v.w = acc[i][3] + bj[3];
        if (act) {
            v.x = fmaxf(v.x, 0.f); v.y = fmaxf(v.y, 0.f);
            v.z = fmaxf(v.z, 0.f); v.w = fmaxf(v.w, 0.f);
        }
        *(float4*)(C + (size_t)row * N + bn + tx * 4) = v;
    }
}

// ---------- wave/block reductions ----------
__device__ __forceinline__ float wave_max(float v) {
#pragma unroll
    for (int o = 32; o; o >>= 1) v = fmaxf(v, __shfl_xor(v, o, 64));
    return v;
}
__device__ __forceinline__ float wave_sum(float v) {
#pragma unroll
    for (int o = 32; o; o >>= 1) v += __shfl_xor(v, o, 64);
    return v;
}

// ---------- softmax over rows of 1024, in place (f32) ----------
__global__ __launch_bounds__(256) void softmax_rows(float* __restrict__ p)
{
    const int b = blockIdx.x, tid = threadIdx.x;
    const int wid = tid >> 6, lane = tid & 63;
    __shared__ float rmax[4], rsum[4];
    float v[4];
    *(float4*)v = *(const float4*)(p + (size_t)b * DD + tid * 4);
    float m = fmaxf(fmaxf(v[0], v[1]), fmaxf(v[2], v[3]));
    m = wave_max(m);
    if (lane == 0) rmax[wid] = m;
    __syncthreads();
    m = fmaxf(fmaxf(rmax[0], rmax[1]), fmaxf(rmax[2], rmax[3]));
    float e[4], s = 0.f;
#pragma unroll
    for (int i = 0; i < 4; ++i) { e[i] = expf(v[i] - m); s += e[i]; }
    s = wave_sum(s);
    if (lane == 0) rsum[wid] = s;
    __syncthreads();
    s = rsum[0] + rsum[1] + rsum[2] + rsum[3];
    const float inv = 1.0f / s;
    float4 o; o.x = e[0] * inv; o.y = e[1] * inv; o.z = e[2] * inv; o.w = e[3] * inv;
    *(float4*)(p + (size_t)b * DD + tid * 4) = o;
}

// ---------- fused Gumbel-softmax + max-over-K + masked input (all f32) ----------
// one block (256 thr) per batch row; thread t owns d = 4t..4t+3
__global__ __launch_bounds__(256) void gumbel_mask_kernel(
    const float* __restrict__ uniform,   // [B,K,D] f32
    const float* __restrict__ x,         // [B,D] f32
    const float* __restrict__ logits,    // [B,D] f32 (softmaxed)
    float* __restrict__ masks,           // [B,D] f32 out (d_out+4096)
    float* __restrict__ newin)           // [B,D] f32 ws
{
    const int b = blockIdx.x, tid = threadIdx.x;
    const int wid = tid >> 6, lane = tid & 63;
    const int d0 = tid * 4;
    __shared__ float rmax[4], rsum[4];

    float lg[4];
    *(float4*)lg = *(const float4*)(logits + (size_t)b * DD + d0);
    float mk[4] = {0.f, 0.f, 0.f, 0.f};

    const float* up = uniform + (size_t)b * KK * DD + d0;
    for (int k = 0; k < KK; ++k) {
        float u[4], n[4];
        *(float4*)u = *(const float4*)(up + (size_t)k * DD);
#pragma unroll
        for (int i = 0; i < 4; ++i)
            n[i] = -logf(-logf(u[i])) + lg[i];   // u in [TINY, 1): finite

        float m = fmaxf(fmaxf(n[0], n[1]), fmaxf(n[2], n[3]));
        m = wave_max(m);
        if (lane == 0) rmax[wid] = m;
        __syncthreads();
        m = fmaxf(fmaxf(rmax[0], rmax[1]), fmaxf(rmax[2], rmax[3]));

        float e[4], s = 0.f;
#pragma unroll
        for (int i = 0; i < 4; ++i) { e[i] = expf(n[i] - m); s += e[i]; }
        s = wave_sum(s);
        if (lane == 0) rsum[wid] = s;
        __syncthreads();
        s = rsum[0] + rsum[1] + rsum[2] + rsum[3];
        const float inv = 1.0f / s;
#pragma unroll
        for (int i = 0; i < 4; ++i) mk[i] = fmaxf(mk[i], e[i] * inv);
        __syncthreads();
    }

    float xv[4];
    *(float4*)xv = *(const float4*)(x + (size_t)b * DD + d0);
    *(float4*)(masks + (size_t)b * DD + d0) = *(float4*)mk;
    float4 ni;
    ni.x = xv[0] * mk[0]; ni.y = xv[1] * mk[1];
    ni.z = xv[2] * mk[2]; ni.w = xv[3] * mk[3];
    *(float4*)(newin + (size_t)b * DD + d0) = ni;
}

// ---------- final: deep_out[B,2] = hp @ wp1 + bp1 (f32 out) ----------
__global__ __launch_bounds__(256) void final_kernel(
    const float* __restrict__ hp, const float* __restrict__ wp1,
    const float* __restrict__ bp1, float* __restrict__ out)
{
    const int wid = threadIdx.x >> 6, lane = threadIdx.x & 63;
    const int row = blockIdx.x * 4 + wid;
    const float* hrow = hp + (size_t)row * HH;
    float a0 = 0.f, a1 = 0.f;
#pragma unroll
    for (int j = 0; j < 8; ++j) {
        const int k = j * 64 + lane;
        const float h = hrow[k];
        const float2 w = *(const float2*)(wp1 + k * 2);
        a0 += h * w.x; a1 += h * w.y;
    }
    a0 = wave_sum(a0); a1 = wave_sum(a1);
    if (lane == 0) {
        out[row * 2 + 0] = a0 + bp1[0];
        out[row * 2 + 1] = a1 + bp1[1];
    }
}

extern "C" void kernel_launch(void* const* d_in, const int* in_sizes, int n_in,
                              void* d_out, int out_size, void* d_ws, size_t ws_size,
                              hipStream_t stream)
{
    (void)in_sizes; (void)n_in; (void)out_size; (void)ws_size;

    const float* x    = (const float*)d_in[0];
    const float* uni  = (const float*)d_in[1];
    const float* w0   = (const float*)d_in[2];
    const float* b0   = (const float*)d_in[3];
    const float* w1   = (const float*)d_in[4];
    const float* b1   = (const float*)d_in[5];
    const float* wout = (const float*)d_in[6];
    const float* bout = (const float*)d_in[7];
    const float* wp0  = (const float*)d_in[8];
    const float* bp0  = (const float*)d_in[9];
    const float* wp1  = (const float*)d_in[10];
    const float* bp1  = (const float*)d_in[11];
    // d_in[12] = k (scalar 32), unused — KK is compile-time

    float* ws = (float*)d_ws;
    float* out   = (float*)d_out;            // deep_out [2048,2] f32
    float* masks = out + (size_t)BB * 2;     // masks [2048,1024] f32

    // h0 = relu(x @ w0 + b0)            [2048,512]
    gemm_f32<<<dim3(HH / 64, BB / 64), 256, 0, stream>>>(
        x, w0, b0, ws + OFF_H0, BB, HH, DD, 1);

    // h1 = relu(h0 @ w1 + b1)           [2048,512]
    gemm_f32<<<dim3(HH / 64, BB / 64), 256, 0, stream>>>(
        ws + OFF_H0, w1, b1, ws + OFF_H1, BB, HH, HH, 1);

    // logits_pre = h1 @ wout + bout     [2048,1024]
    gemm_f32<<<dim3(DD / 64, BB / 64), 256, 0, stream>>>(
        ws + OFF_H1, wout, bout, ws + OFF_LG, BB, DD, HH, 0);

    // logits = softmax(rows)
    softmax_rows<<<BB, 256, 0, stream>>>(ws + OFF_LG);

    // gumbel-softmax -> masks (f32 out) + new_inputs (f32 ws)
    gumbel_mask_kernel<<<BB, 256, 0, stream>>>(uni, x, ws + OFF_LG, masks, ws + OFF_NEWIN);

    // hp = relu(new_inputs @ wp0 + bp0) [2048,512]
    gemm_f32<<<dim3(HH / 64, BB / 64), 256, 0, stream>>>(
        ws + OFF_NEWIN, wp0, bp0, ws + OFF_HP, BB, HH, DD, 1);

    // deep_out = hp @ wp1 + bp1         [2048,2]
    final_kernel<<<BB / 4, 256, 0, stream>>>(ws + OFF_HP, wp1, bp1, out);
}

// Round 4
// 453.772 us; speedup vs baseline: 1.3599x; 1.3599x over previous
//
#include <hip/hip_runtime.h>

// Fixed dims: B=2048, D=1024, H=512, K=32, OUT=2
#define BB 2048
#define DD 1024
#define HH 512
#define KK 32

#define AS_GLOBAL __attribute__((address_space(1)))
#define AS_LDS    __attribute__((address_space(3)))

typedef __attribute__((ext_vector_type(8))) short short8;   // 8 bf16 (4 VGPRs)
typedef __attribute__((ext_vector_type(4))) float floatx4;  // MFMA acc

__device__ __forceinline__ float bf2f(unsigned short u) {
    union { unsigned int u; float f; } c; c.u = ((unsigned int)u) << 16; return c.f;
}
__device__ __forceinline__ unsigned short f2bf(float f) {
    union { float f; unsigned int u; } c; c.f = f;
    unsigned int u = c.u + 0x7FFFu + ((c.u >> 16) & 1u);
    return (unsigned short)(u >> 16);
}

// ---------------- workspace layout (byte offsets) ----------------
#define WOFF_XB    ((size_t)0)          // x bf16 [2048,1024]           4 MB
#define WOFF_W0T   ((size_t)4194304)    // w0^T bf16 [512,1024]         1 MB
#define WOFF_W1T   ((size_t)5242880)    // w1^T bf16 [512,512]          .5 MB
#define WOFF_WOUTT ((size_t)5767168)    // wout^T bf16 [1024,512]       1 MB
#define WOFF_WP0T  ((size_t)6815744)    // wp0^T bf16 [512,1024]        1 MB
#define WOFF_H0    ((size_t)7864320)    // h0 bf16 [2048,512]           2 MB
#define WOFF_H1    ((size_t)9961472)    // h1 bf16 [2048,512]           2 MB
#define WOFF_LG    ((size_t)12058624)   // logits_pre f32 [2048,1024]   8 MB
#define WOFF_NEWIN ((size_t)20447232)   // newin bf16 [2048,1024]       4 MB
#define WOFF_HP    ((size_t)24641536)   // hp bf16 [2048,512]           2 MB
// end ~26.6 MB (ws is >= 1 GB per round-3 profile)

// ---------------- prep: x convert + 4 weight transpose-converts ----------------
// grid = 2816 blocks x 256 thr.
// [0,1024): x convert (2048 elems/block). [1024,1536): w0T. [1536,1792): w1T.
// [1792,2304): woutT. [2304,2816): wp0T.
__global__ __launch_bounds__(256) void prep_kernel(
    const float* __restrict__ x,  const float* __restrict__ w0,
    const float* __restrict__ w1, const float* __restrict__ wout,
    const float* __restrict__ wp0, unsigned short* __restrict__ ws)
{
    const int blk = blockIdx.x;
    if (blk < 1024) {
        unsigned short* xb = ws + WOFF_XB / 2;
        const size_t base = (size_t)blk * 2048 + (size_t)threadIdx.x * 8;
        float4 v0 = *(const float4*)(x + base);
        float4 v1 = *(const float4*)(x + base + 4);
        ushort4 o0, o1;
        o0.x = f2bf(v0.x); o0.y = f2bf(v0.y); o0.z = f2bf(v0.z); o0.w = f2bf(v0.w);
        o1.x = f2bf(v1.x); o1.y = f2bf(v1.y); o1.z = f2bf(v1.z); o1.w = f2bf(v1.w);
        *(ushort4*)(xb + base) = o0;
        *(ushort4*)(xb + base + 4) = o1;
        return;
    }
    const float* src; unsigned short* dst; int Kd, N, t;
    if (blk < 1536)      { src = w0;   dst = ws + WOFF_W0T / 2;   Kd = 1024; N = 512;  t = blk - 1024; }
    else if (blk < 1792) { src = w1;   dst = ws + WOFF_W1T / 2;   Kd = 512;  N = 512;  t = blk - 1536; }
    else if (blk < 2304) { src = wout; dst = ws + WOFF_WOUTT / 2; Kd = 512;  N = 1024; t = blk - 1792; }
    else                 { src = wp0;  dst = ws + WOFF_WP0T / 2;  Kd = 1024; N = 512;  t = blk - 2304; }
    const int ntn = N / 32;
    const int kt = t / ntn, nt = t % ntn;
    __shared__ float tile[32][33];
    const int tx = threadIdx.x & 31, ty = threadIdx.x >> 5;   // 32 x 8
#pragma unroll
    for (int r = 0; r < 32; r += 8)
        tile[ty + r][tx] = src[(size_t)(kt * 32 + ty + r) * N + nt * 32 + tx];
    __syncthreads();
#pragma unroll
    for (int r = 0; r < 32; r += 8)
        dst[(size_t)(nt * 32 + ty + r) * Kd + kt * 32 + tx] = f2bf(tile[tx][ty + r]);
}

// ---------------- bf16 MFMA GEMM: C[M,N] = act(A[M,K] @ B^T[N,K]^T + bias) ----------------
// 64x64 tile, BK=32, 256 thr = 4 waves (each 32x32 via 2x2 of 16x16x32 frags).
template <int RELU, int OUTBF>
__global__ __launch_bounds__(256) void gemm_mfma(
    const unsigned short* __restrict__ A,   // [M,K] bf16 row-major
    const unsigned short* __restrict__ BT,  // [N,K] bf16 row-major (W transposed)
    const float* __restrict__ bias,         // [N] f32
    void* __restrict__ Cv, int M, int N, int Kd)
{
    __shared__ __align__(16) unsigned short As[64 * 32];
    __shared__ __align__(16) unsigned short Bs[64 * 32];
    const int tid = threadIdx.x;
    const int bm = blockIdx.y * 64, bn = blockIdx.x * 64;
    const int wave = tid >> 6, lane = tid & 63;

    floatx4 acc[2][2] = {};

    // staging: thread tid loads 16B = 8 bf16; tile row sr, cols sc..sc+7
    const int sr = tid >> 2, sc = (tid & 3) * 8;
    const unsigned short* ga = A  + (size_t)(bm + sr) * Kd + sc;
    const unsigned short* gb = BT + (size_t)(bn + sr) * Kd + sc;
    unsigned short* lA = As + (size_t)wave * 512;   // wave-uniform base (64 lanes * 16B)
    unsigned short* lB = Bs + (size_t)wave * 512;

    // fragment read addresses (LDS row-major [64][32])
    const int wm = (wave >> 1) * 32, wn = (wave & 1) * 32;
    const int fr = lane & 15, fk = (lane >> 4) * 8;
    const unsigned short* pa0 = As + (wm + fr) * 32 + fk;
    const unsigned short* pb0 = Bs + (wn + fr) * 32 + fk;

    for (int k0 = 0; k0 < Kd; k0 += 32) {
        __builtin_amdgcn_global_load_lds((const AS_GLOBAL void*)(ga + k0),
                                         (AS_LDS void*)lA, 16, 0, 0);
        __builtin_amdgcn_global_load_lds((const AS_GLOBAL void*)(gb + k0),
                                         (AS_LDS void*)lB, 16, 0, 0);
        __syncthreads();   // compiler drains vmcnt before barrier
        short8 a0 = *(const short8*)pa0;
        short8 a1 = *(const short8*)(pa0 + 16 * 32);
        short8 b0 = *(const short8*)pb0;
        short8 b1 = *(const short8*)(pb0 + 16 * 32);
        acc[0][0] = __builtin_amdgcn_mfma_f32_16x16x32_bf16(a0, b0, acc[0][0], 0, 0, 0);
        acc[0][1] = __builtin_amdgcn_mfma_f32_16x16x32_bf16(a0, b1, acc[0][1], 0, 0, 0);
        acc[1][0] = __builtin_amdgcn_mfma_f32_16x16x32_bf16(a1, b0, acc[1][0], 0, 0, 0);
        acc[1][1] = __builtin_amdgcn_mfma_f32_16x16x32_bf16(a1, b1, acc[1][1], 0, 0, 0);
        __syncthreads();   // all reads done before next staging overwrites
    }

    // epilogue: C/D layout col = lane&15, row = (lane>>4)*4 + reg  [m89/m91-verified]
    float* Cf = (float*)Cv;
    unsigned short* Cb = (unsigned short*)Cv;
    const int er = (lane >> 4) * 4, ec = lane & 15;
#pragma unroll
    for (int i = 0; i < 2; ++i)
#pragma unroll
        for (int j = 0; j < 2; ++j) {
            const int col = bn + wn + j * 16 + ec;
            const float bv = bias[col];
#pragma unroll
            for (int r = 0; r < 4; ++r) {
                const int row = bm + wm + i * 16 + er + r;
                float v = acc[i][j][r] + bv;
                if (RELU) v = fmaxf(v, 0.0f);
                if (OUTBF) Cb[(size_t)row * N + col] = f2bf(v);
                else       Cf[(size_t)row * N + col] = v;
            }
        }
}

// ---------------- wave reductions ----------------
__device__ __forceinline__ float wave_max(float v) {
#pragma unroll
    for (int o = 32; o; o >>= 1) v = fmaxf(v, __shfl_xor(v, o, 64));
    return v;
}
__device__ __forceinline__ float wave_sum(float v) {
#pragma unroll
    for (int o = 32; o; o >>= 1) v += __shfl_xor(v, o, 64);
    return v;
}

// ---------------- fused softmax(logits) + gumbel-softmax + max-K + mask ----------------
// One WAVE per batch row (barrier-free). 256 thr = 4 rows/block, grid 512.
// Trick: sample_i = exp(p_i) * (1/(-log u_i)) / sum  — exp(p) hoisted out of k-loop.
__global__ __launch_bounds__(256) void gumbel_fused(
    const float* __restrict__ lgpre,    // [B,D] logits pre-softmax (f32)
    const float* __restrict__ uniform,  // [B,K,D] f32
    const float* __restrict__ x,        // [B,D] f32
    float* __restrict__ masks,          // [B,D] f32 -> d_out+4096
    unsigned short* __restrict__ newin) // [B,D] bf16
{
    const int wave = threadIdx.x >> 6, lane = threadIdx.x & 63;
    const int b = blockIdx.x * 4 + wave;

    // ---- softmax over the row (selector probabilities p) ----
    float lp[16];
    const float* lrow = lgpre + (size_t)b * DD;
#pragma unroll
    for (int j = 0; j < 4; ++j)
        *(float4*)(lp + j * 4) = *(const float4*)(lrow + lane * 4 + j * 256);
    float M = -1e30f;
#pragma unroll
    for (int i = 0; i < 16; ++i) M = fmaxf(M, lp[i]);
    M = wave_max(M);
    float S = 0.f;
#pragma unroll
    for (int i = 0; i < 16; ++i) { lp[i] = __expf(lp[i] - M); S += lp[i]; }
    S = wave_sum(S);
    const float invS = 1.0f / S;
    float ep[16];
#pragma unroll
    for (int i = 0; i < 16; ++i) ep[i] = __expf(lp[i] * invS);   // exp(p_i)

    // ---- k-loop: concrete relaxation samples, running max ----
    float mk[16] = {0.f,0.f,0.f,0.f,0.f,0.f,0.f,0.f,0.f,0.f,0.f,0.f,0.f,0.f,0.f,0.f};
    const float* up = uniform + (size_t)b * KK * DD;
    for (int k = 0; k < KK; ++k) {
        float sv[16], sloc = 0.f;
#pragma unroll
        for (int j = 0; j < 4; ++j) {
            float4 u4 = *(const float4*)(up + (size_t)k * DD + lane * 4 + j * 256);
            const float uu[4] = {u4.x, u4.y, u4.z, u4.w};
#pragma unroll
            for (int q = 0; q < 4; ++q) {
                const float u = uu[q];
                // t = -log(u). v_log_f32 has terrible RELATIVE error for u->1
                // (exactly the samples that become mask ~= 1), so use a log1p
                // polynomial there; fast log elsewhere.
                const float vv = u - 1.0f;                        // exact in [0.5,1]
                const float tpoly = -vv * (1.0f + vv * (-0.5f + vv * 0.33333333f));
                const float tlog  = -__logf(u);
                const float t = (u > 0.984375f) ? tpoly : tlog;
                const float s = ep[j * 4 + q] / t;
                sv[j * 4 + q] = s;
                sloc += s;
            }
        }
        const float Sk = wave_sum(sloc);
        const float inv = 1.0f / Sk;
#pragma unroll
        for (int i = 0; i < 16; ++i) mk[i] = fmaxf(mk[i], sv[i] * inv);
    }

    // ---- outputs: masks (f32) + new_inputs (bf16) ----
#pragma unroll
    for (int j = 0; j < 4; ++j) {
        const int d = lane * 4 + j * 256;
        float4 xv = *(const float4*)(x + (size_t)b * DD + d);
        float4 mo; mo.x = mk[j*4]; mo.y = mk[j*4+1]; mo.z = mk[j*4+2]; mo.w = mk[j*4+3];
        *(float4*)(masks + (size_t)b * DD + d) = mo;
        ushort4 nb;
        nb.x = f2bf(xv.x * mk[j*4]);   nb.y = f2bf(xv.y * mk[j*4+1]);
        nb.z = f2bf(xv.z * mk[j*4+2]); nb.w = f2bf(xv.w * mk[j*4+3]);
        *(ushort4*)(newin + (size_t)b * DD + d) = nb;
    }
}

// ---------------- final: deep_out[B,2] = hp(bf16) @ wp1 + bp1 ----------------
__global__ __launch_bounds__(256) void final_kernel(
    const unsigned short* __restrict__ hp, const float* __restrict__ wp1,
    const float* __restrict__ bp1, float* __restrict__ out)
{
    const int wave = threadIdx.x >> 6, lane = threadIdx.x & 63;
    const int row = blockIdx.x * 4 + wave;
    const unsigned short* hrow = hp + (size_t)row * HH;
    float a0 = 0.f, a1 = 0.f;
#pragma unroll
    for (int j = 0; j < 8; ++j) {
        const int k = j * 64 + lane;
        const float h = bf2f(hrow[k]);
        const float2 w = *(const float2*)(wp1 + k * 2);
        a0 += h * w.x; a1 += h * w.y;
    }
    a0 = wave_sum(a0); a1 = wave_sum(a1);
    if (lane == 0) {
        out[row * 2 + 0] = a0 + bp1[0];
        out[row * 2 + 1] = a1 + bp1[1];
    }
}

extern "C" void kernel_launch(void* const* d_in, const int* in_sizes, int n_in,
                              void* d_out, int out_size, void* d_ws, size_t ws_size,
                              hipStream_t stream)
{
    (void)in_sizes; (void)n_in; (void)out_size; (void)ws_size;

    const float* x    = (const float*)d_in[0];
    const float* uni  = (const float*)d_in[1];
    const float* w0   = (const float*)d_in[2];
    const float* b0   = (const float*)d_in[3];
    const float* w1   = (const float*)d_in[4];
    const float* b1   = (const float*)d_in[5];
    const float* wout = (const float*)d_in[6];
    const float* bout = (const float*)d_in[7];
    const float* wp0  = (const float*)d_in[8];
    const float* bp0  = (const float*)d_in[9];
    const float* wp1  = (const float*)d_in[10];
    const float* bp1  = (const float*)d_in[11];

    unsigned char* ws = (unsigned char*)d_ws;
    unsigned short* xb    = (unsigned short*)(ws + WOFF_XB);
    unsigned short* w0T   = (unsigned short*)(ws + WOFF_W0T);
    unsigned short* w1T   = (unsigned short*)(ws + WOFF_W1T);
    unsigned short* woutT = (unsigned short*)(ws + WOFF_WOUTT);
    unsigned short* wp0T  = (unsigned short*)(ws + WOFF_WP0T);
    unsigned short* h0    = (unsigned short*)(ws + WOFF_H0);
    unsigned short* h1    = (unsigned short*)(ws + WOFF_H1);
    float*          lg    = (float*)(ws + WOFF_LG);
    unsigned short* newin = (unsigned short*)(ws + WOFF_NEWIN);
    unsigned short* hp    = (unsigned short*)(ws + WOFF_HP);

    float* out   = (float*)d_out;            // deep_out [2048,2]
    float* masks = out + (size_t)BB * 2;     // masks [2048,1024]

    // 1. convert + transpose params
    prep_kernel<<<2816, 256, 0, stream>>>(x, w0, w1, wout, wp0, (unsigned short*)ws);

    // 2. h0 = relu(x @ w0 + b0)            [2048,512] bf16
    gemm_mfma<1, 1><<<dim3(HH / 64, BB / 64), 256, 0, stream>>>(xb, w0T, b0, h0, BB, HH, DD);

    // 3. h1 = relu(h0 @ w1 + b1)           [2048,512] bf16
    gemm_mfma<1, 1><<<dim3(HH / 64, BB / 64), 256, 0, stream>>>(h0, w1T, b1, h1, BB, HH, HH);

    // 4. logits_pre = h1 @ wout + bout     [2048,1024] f32
    gemm_mfma<0, 0><<<dim3(DD / 64, BB / 64), 256, 0, stream>>>(h1, woutT, bout, lg, BB, DD, HH);

    // 5.+6. softmax + gumbel + max-K + mask (fused; wave per row)
    gumbel_fused<<<BB / 4, 256, 0, stream>>>(lg, uni, x, masks, newin);

    // 7. hp = relu(newin @ wp0 + bp0)      [2048,512] bf16
    gemm_mfma<1, 1><<<dim3(HH / 64, BB / 64), 256, 0, stream>>>(newin, wp0T, bp0, hp, BB, HH, DD);

    // 8. deep_out = hp @ wp1 + bp1         [2048,2] f32
    final_kernel<<<BB / 4, 256, 0, stream>>>(hp, wp1, bp1, out);
}

// Round 5
// 447.096 us; speedup vs baseline: 1.3802x; 1.0149x over previous
//
#include <hip/hip_runtime.h>

// Fixed dims: B=2048, D=1024, H=512, K=32, OUT=2
#define BB 2048
#define DD 1024
#define HH 512
#define KK 32

#define AS_GLOBAL __attribute__((address_space(1)))
#define AS_LDS    __attribute__((address_space(3)))

typedef __attribute__((ext_vector_type(8))) short short8;   // 8 bf16 (4 VGPRs)
typedef __attribute__((ext_vector_type(4))) float floatx4;  // MFMA acc

__device__ __forceinline__ float bf2f(unsigned short u) {
    union { unsigned int u; float f; } c; c.u = ((unsigned int)u) << 16; return c.f;
}
__device__ __forceinline__ unsigned short f2bf(float f) {
    union { float f; unsigned int u; } c; c.f = f;
    unsigned int u = c.u + 0x7FFFu + ((c.u >> 16) & 1u);
    return (unsigned short)(u >> 16);
}

// ---------------- workspace layout (byte offsets) ----------------
#define WOFF_XB    ((size_t)0)          // x bf16 [2048,1024]           4 MB
#define WOFF_W0T   ((size_t)4194304)    // w0^T bf16 [512,1024]         1 MB
#define WOFF_W1T   ((size_t)5242880)    // w1^T bf16 [512,512]          .5 MB
#define WOFF_WOUTT ((size_t)5767168)    // wout^T bf16 [1024,512]       1 MB
#define WOFF_WP0T  ((size_t)6815744)    // wp0^T bf16 [512,1024]        1 MB
#define WOFF_H0    ((size_t)7864320)    // h0 bf16 [2048,512]           2 MB
#define WOFF_H1    ((size_t)9961472)    // h1 bf16 [2048,512]           2 MB
#define WOFF_LG    ((size_t)12058624)   // logits_pre f32 [2048,1024]   8 MB
#define WOFF_NEWIN ((size_t)20447232)   // newin bf16 [2048,1024]       4 MB
#define WOFF_HP    ((size_t)24641536)   // hp bf16 [2048,512]           2 MB

// ---------------- prep: x convert + 4 weight transpose-converts ----------------
__global__ __launch_bounds__(256) void prep_kernel(
    const float* __restrict__ x,  const float* __restrict__ w0,
    const float* __restrict__ w1, const float* __restrict__ wout,
    const float* __restrict__ wp0, unsigned short* __restrict__ ws)
{
    const int blk = blockIdx.x;
    if (blk < 1024) {
        unsigned short* xb = ws + WOFF_XB / 2;
        const size_t base = (size_t)blk * 2048 + (size_t)threadIdx.x * 8;
        float4 v0 = *(const float4*)(x + base);
        float4 v1 = *(const float4*)(x + base + 4);
        ushort4 o0, o1;
        o0.x = f2bf(v0.x); o0.y = f2bf(v0.y); o0.z = f2bf(v0.z); o0.w = f2bf(v0.w);
        o1.x = f2bf(v1.x); o1.y = f2bf(v1.y); o1.z = f2bf(v1.z); o1.w = f2bf(v1.w);
        *(ushort4*)(xb + base) = o0;
        *(ushort4*)(xb + base + 4) = o1;
        return;
    }
    const float* src; unsigned short* dst; int Kd, N, t;
    if (blk < 1536)      { src = w0;   dst = ws + WOFF_W0T / 2;   Kd = 1024; N = 512;  t = blk - 1024; }
    else if (blk < 1792) { src = w1;   dst = ws + WOFF_W1T / 2;   Kd = 512;  N = 512;  t = blk - 1536; }
    else if (blk < 2304) { src = wout; dst = ws + WOFF_WOUTT / 2; Kd = 512;  N = 1024; t = blk - 1792; }
    else                 { src = wp0;  dst = ws + WOFF_WP0T / 2;  Kd = 1024; N = 512;  t = blk - 2304; }
    const int ntn = N / 32;
    const int kt = t / ntn, nt = t % ntn;
    __shared__ float tile[32][33];
    const int tx = threadIdx.x & 31, ty = threadIdx.x >> 5;   // 32 x 8
#pragma unroll
    for (int r = 0; r < 32; r += 8)
        tile[ty + r][tx] = src[(size_t)(kt * 32 + ty + r) * N + nt * 32 + tx];
    __syncthreads();
#pragma unroll
    for (int r = 0; r < 32; r += 8)
        dst[(size_t)(nt * 32 + ty + r) * Kd + kt * 32 + tx] = f2bf(tile[tx][ty + r]);
}

// ---------------- bf16 MFMA GEMM, BK=64, double-buffered, XOR-swizzled LDS ------
// C[M,N] = act(A[M,K] @ BT[N,K]^T + bias). 64x64 tile, 256 thr = 4 waves.
// LDS layout: 16B chunk (row r, kchunk kc) at unit u = r*8 + (kc ^ (r&7)).
// global_load_lds staging (unit = tid) inverts this; frag ds_reads then hit
// 2 lanes/bank-group = conflict-free (m136: 2-way is free).
template <int RELU, int OUTBF>
__global__ __launch_bounds__(256) void gemm_mfma(
    const unsigned short* __restrict__ A,   // [M,K] bf16 row-major
    const unsigned short* __restrict__ BT,  // [N,K] bf16 row-major
    const float* __restrict__ bias,         // [N] f32
    void* __restrict__ Cv, int M, int N, int Kd)
{
    __shared__ __align__(16) unsigned short As[2][4096];   // 2 x 8 KB
    __shared__ __align__(16) unsigned short Bs[2][4096];
    const int tid = threadIdx.x;
    const int bm = blockIdx.y * 64, bn = blockIdx.x * 64;
    const int wave = tid >> 6, lane = tid & 63;

    floatx4 acc[2][2] = {};

    // staging source mapping (inverse of the swizzle), same for both 32-row halves
    const int sr = tid >> 3;                           // row 0..31 (half 1), +32 (half 2)
    const int skc = (tid & 7) ^ ((tid >> 3) & 7);      // permuted k-chunk
    const unsigned short* ga = A  + (size_t)(bm + sr) * Kd + skc * 8;
    const unsigned short* ga2 = ga + (size_t)32 * Kd;
    const unsigned short* gb = BT + (size_t)(bn + sr) * Kd + skc * 8;
    const unsigned short* gb2 = gb + (size_t)32 * Kd;
    const int ldoff = wave * 512;                      // ushorts: wave-uniform base

    // fragment read indices
    const int wm = (wave >> 1) * 32, wn = (wave & 1) * 32;
    const int fr = lane & 15, fq = lane >> 4;          // frag row, k-quad
    int ua[2], ub[2];
#pragma unroll
    for (int i = 0; i < 2; ++i) {
        const int ra = wm + i * 16 + fr;
        const int rb = wn + i * 16 + fr;
        ua[i] = ra * 8;  ub[i] = rb * 8;               // ^ (kc ^ (r&7)) added per t
    }

    const int steps = Kd >> 6;

#define STAGE(buf, k0)                                                              \
    do {                                                                            \
        __builtin_amdgcn_global_load_lds((const AS_GLOBAL void*)(ga + (k0)),        \
            (AS_LDS void*)(&As[buf][0] + ldoff), 16, 0, 0);                         \
        __builtin_amdgcn_global_load_lds((const AS_GLOBAL void*)(ga2 + (k0)),       \
            (AS_LDS void*)(&As[buf][2048] + ldoff), 16, 0, 0);                      \
        __builtin_amdgcn_global_load_lds((const AS_GLOBAL void*)(gb + (k0)),        \
            (AS_LDS void*)(&Bs[buf][0] + ldoff), 16, 0, 0);                         \
        __builtin_amdgcn_global_load_lds((const AS_GLOBAL void*)(gb2 + (k0)),       \
            (AS_LDS void*)(&Bs[buf][2048] + ldoff), 16, 0, 0);                      \
    } while (0)

    STAGE(0, 0);
    __syncthreads();

    for (int s = 0; s < steps; ++s) {
        const int buf = s & 1;
        if (s + 1 < steps) STAGE((s + 1) & 1, (s + 1) << 6);   // prefetch overlaps MFMA below
#pragma unroll
        for (int t = 0; t < 2; ++t) {
            short8 a[2], b[2];
#pragma unroll
            for (int i = 0; i < 2; ++i) {
                const int kc = t * 4 + fq;
                const int eA = (wm + i * 16 + fr) & 7;
                const int eB = (wn + i * 16 + fr) & 7;
                a[i] = *(const short8*)(&As[buf][0] + (size_t)(ua[i] + (kc ^ eA)) * 8);
                b[i] = *(const short8*)(&Bs[buf][0] + (size_t)(ub[i] + (kc ^ eB)) * 8);
            }
            acc[0][0] = __builtin_amdgcn_mfma_f32_16x16x32_bf16(a[0], b[0], acc[0][0], 0, 0, 0);
            acc[0][1] = __builtin_amdgcn_mfma_f32_16x16x32_bf16(a[0], b[1], acc[0][1], 0, 0, 0);
            acc[1][0] = __builtin_amdgcn_mfma_f32_16x16x32_bf16(a[1], b[0], acc[1][0], 0, 0, 0);
            acc[1][1] = __builtin_amdgcn_mfma_f32_16x16x32_bf16(a[1], b[1], acc[1][1], 0, 0, 0);
        }
        __syncthreads();
    }
#undef STAGE

    // epilogue: C/D layout col = lane&15, row = (lane>>4)*4 + reg
    float* Cf = (float*)Cv;
    unsigned short* Cb = (unsigned short*)Cv;
    const int er = fq * 4, ec = fr;
#pragma unroll
    for (int i = 0; i < 2; ++i)
#pragma unroll
        for (int j = 0; j < 2; ++j) {
            const int col = bn + wn + j * 16 + ec;
            const float bv = bias[col];
#pragma unroll
            for (int r = 0; r < 4; ++r) {
                const int row = bm + wm + i * 16 + er + r;
                float v = acc[i][j][r] + bv;
                if (RELU) v = fmaxf(v, 0.0f);
                if (OUTBF) Cb[(size_t)row * N + col] = f2bf(v);
                else       Cf[(size_t)row * N + col] = v;
            }
        }
}

// ---------------- wave reductions ----------------
__device__ __forceinline__ float wave_max(float v) {
#pragma unroll
    for (int o = 32; o; o >>= 1) v = fmaxf(v, __shfl_xor(v, o, 64));
    return v;
}
__device__ __forceinline__ float wave_sum(float v) {
#pragma unroll
    for (int o = 32; o; o >>= 1) v += __shfl_xor(v, o, 64);
    return v;
}

// ---------------- fused softmax(logits) + gumbel-softmax + max-K + mask ----------
// One WAVE per row. Algebra: sample_i = ep_i/t_i / sum, t = -log(u).
// Using t' = -log2(u): the ln2 factor cancels in the ratio -> raw v_log_f32.
// Division -> v_rcp_f32 (1 ulp; samples are ratios, error cancels further).
__global__ __launch_bounds__(256) void gumbel_fused(
    const float* __restrict__ lgpre,    // [B,D] logits pre-softmax (f32)
    const float* __restrict__ uniform,  // [B,K,D] f32
    const float* __restrict__ x,        // [B,D] f32
    float* __restrict__ masks,          // [B,D] f32 -> d_out+4096
    unsigned short* __restrict__ newin) // [B,D] bf16
{
    const int wave = threadIdx.x >> 6, lane = threadIdx.x & 63;
    const int b = blockIdx.x * 4 + wave;

    // ---- softmax over the row (selector probabilities p) ----
    float lp[16];
    const float* lrow = lgpre + (size_t)b * DD;
#pragma unroll
    for (int j = 0; j < 4; ++j)
        *(float4*)(lp + j * 4) = *(const float4*)(lrow + lane * 4 + j * 256);
    float M = -1e30f;
#pragma unroll
    for (int i = 0; i < 16; ++i) M = fmaxf(M, lp[i]);
    M = wave_max(M);
    float S = 0.f;
#pragma unroll
    for (int i = 0; i < 16; ++i) { lp[i] = __expf(lp[i] - M); S += lp[i]; }
    S = wave_sum(S);
    const float invS = 1.0f / S;
    float ep[16];
#pragma unroll
    for (int i = 0; i < 16; ++i) ep[i] = __expf(lp[i] * invS);   // exp(p_i)

    // ---- k-loop ----
    float mk[16] = {0.f,0.f,0.f,0.f,0.f,0.f,0.f,0.f,0.f,0.f,0.f,0.f,0.f,0.f,0.f,0.f};
    const float* up = uniform + (size_t)b * KK * DD;
    for (int k = 0; k < KK; ++k) {
        float sv[16], sloc = 0.f;
#pragma unroll
        for (int j = 0; j < 4; ++j) {
            float4 u4 = *(const float4*)(up + (size_t)k * DD + lane * 4 + j * 256);
            const float uu[4] = {u4.x, u4.y, u4.z, u4.w};
#pragma unroll
            for (int q = 0; q < 4; ++q) {
                const float u = uu[q];
                // t' = -log2(u); v_log_f32 has poor RELATIVE accuracy for u->1
                // (abs err ~2^-22 on a ~0 result) — exactly the mask~1 samples —
                // so use the series there. -log2(u) = -v*(1/ln2 - v/(2ln2) + v^2/(3ln2))
                const float vv = u - 1.0f;
                const float tpoly = -vv * (1.4426950f + vv * (-0.7213475f + vv * 0.4808983f));
                const float tlog  = -__builtin_amdgcn_logf(u);   // v_log_f32 = log2
                const float t = (u > 0.984375f) ? tpoly : tlog;
                const float s = ep[j * 4 + q] * __builtin_amdgcn_rcpf(t);
                sv[j * 4 + q] = s;
                sloc += s;
            }
        }
        const float Sk = wave_sum(sloc);
        const float inv = __builtin_amdgcn_rcpf(Sk);
#pragma unroll
        for (int i = 0; i < 16; ++i) mk[i] = fmaxf(mk[i], sv[i] * inv);
    }

    // ---- outputs ----
#pragma unroll
    for (int j = 0; j < 4; ++j) {
        const int d = lane * 4 + j * 256;
        float4 xv = *(const float4*)(x + (size_t)b * DD + d);
        float4 mo; mo.x = mk[j*4]; mo.y = mk[j*4+1]; mo.z = mk[j*4+2]; mo.w = mk[j*4+3];
        *(float4*)(masks + (size_t)b * DD + d) = mo;
        ushort4 nb;
        nb.x = f2bf(xv.x * mk[j*4]);   nb.y = f2bf(xv.y * mk[j*4+1]);
        nb.z = f2bf(xv.z * mk[j*4+2]); nb.w = f2bf(xv.w * mk[j*4+3]);
        *(ushort4*)(newin + (size_t)b * DD + d) = nb;
    }
}

// ---------------- final: deep_out[B,2] = hp(bf16) @ wp1 + bp1 ----------------
__global__ __launch_bounds__(256) void final_kernel(
    const unsigned short* __restrict__ hp, const float* __restrict__ wp1,
    const float* __restrict__ bp1, float* __restrict__ out)
{
    const int wave = threadIdx.x >> 6, lane = threadIdx.x & 63;
    const int row = blockIdx.x * 4 + wave;
    const unsigned short* hrow = hp + (size_t)row * HH;
    float a0 = 0.f, a1 = 0.f;
#pragma unroll
    for (int j = 0; j < 8; ++j) {
        const int k = j * 64 + lane;
        const float h = bf2f(hrow[k]);
        const float2 w = *(const float2*)(wp1 + k * 2);
        a0 += h * w.x; a1 += h * w.y;
    }
    a0 = wave_sum(a0); a1 = wave_sum(a1);
    if (lane == 0) {
        out[row * 2 + 0] = a0 + bp1[0];
        out[row * 2 + 1] = a1 + bp1[1];
    }
}

extern "C" void kernel_launch(void* const* d_in, const int* in_sizes, int n_in,
                              void* d_out, int out_size, void* d_ws, size_t ws_size,
                              hipStream_t stream)
{
    (void)in_sizes; (void)n_in; (void)out_size; (void)ws_size;

    const float* x    = (const float*)d_in[0];
    const float* uni  = (const float*)d_in[1];
    const float* w0   = (const float*)d_in[2];
    const float* b0   = (const float*)d_in[3];
    const float* w1   = (const float*)d_in[4];
    const float* b1   = (const float*)d_in[5];
    const float* wout = (const float*)d_in[6];
    const float* bout = (const float*)d_in[7];
    const float* wp0  = (const float*)d_in[8];
    const float* bp0  = (const float*)d_in[9];
    const float* wp1  = (const float*)d_in[10];
    const float* bp1  = (const float*)d_in[11];

    unsigned char* ws = (unsigned char*)d_ws;
    unsigned short* xb    = (unsigned short*)(ws + WOFF_XB);
    unsigned short* w0T   = (unsigned short*)(ws + WOFF_W0T);
    unsigned short* w1T   = (unsigned short*)(ws + WOFF_W1T);
    unsigned short* woutT = (unsigned short*)(ws + WOFF_WOUTT);
    unsigned short* wp0T  = (unsigned short*)(ws + WOFF_WP0T);
    unsigned short* h0    = (unsigned short*)(ws + WOFF_H0);
    unsigned short* h1    = (unsigned short*)(ws + WOFF_H1);
    float*          lg    = (float*)(ws + WOFF_LG);
    unsigned short* newin = (unsigned short*)(ws + WOFF_NEWIN);
    unsigned short* hp    = (unsigned short*)(ws + WOFF_HP);

    float* out   = (float*)d_out;            // deep_out [2048,2]
    float* masks = out + (size_t)BB * 2;     // masks [2048,1024]

    prep_kernel<<<2816, 256, 0, stream>>>(x, w0, w1, wout, wp0, (unsigned short*)ws);

    gemm_mfma<1, 1><<<dim3(HH / 64, BB / 64), 256, 0, stream>>>(xb, w0T, b0, h0, BB, HH, DD);
    gemm_mfma<1, 1><<<dim3(HH / 64, BB / 64), 256, 0, stream>>>(h0, w1T, b1, h1, BB, HH, HH);
    gemm_mfma<0, 0><<<dim3(DD / 64, BB / 64), 256, 0, stream>>>(h1, woutT, bout, lg, BB, DD, HH);

    gumbel_fused<<<BB / 4, 256, 0, stream>>>(lg, uni, x, masks, newin);

    gemm_mfma<1, 1><<<dim3(HH / 64, BB / 64), 256, 0, stream>>>(newin, wp0T, bp0, hp, BB, HH, DD);
    final_kernel<<<BB / 4, 256, 0, stream>>>(hp, wp1, bp1, out);
}